// Round 2
// baseline (297.565 us; speedup 1.0000x reference)
//
#include <hip/hip_runtime.h>
#include <hip/hip_cooperative_groups.h>

namespace cg = cooperative_groups;

// GAE reverse scan: adv[t] = delta[t] + (gamma*lambda)*adv[t+1]
// delta[t] = reward[t] + gamma*value[t+1] - value[t]
// Fused chunked linear-recurrence: per-thread chunk of L=16 timesteps held in
// registers; chunk sums S exchanged through d_ws across a grid-wide sync.

constexpr int T_ = 1024;
constexpr int B_ = 16384;
constexpr int L_ = 16;        // chunk length
constexpr int C_ = T_ / L_;   // 64 chunks
constexpr float GAMMA = 0.99f;
constexpr float COEF  = (float)(0.99 * 0.97);

__host__ __device__ constexpr float pow_coef(int n) {
    float p = 1.0f;
    for (int i = 0; i < n; ++i) p *= COEF;
    return p;
}
constexpr float CL = pow_coef(L_);   // COEF^L

__device__ __forceinline__ float4 fmaf4(float4 a, float c, float4 b) {
    // a + c*b componentwise
    return make_float4(a.x + c * b.x, a.y + c * b.y, a.z + c * b.z, a.w + c * b.w);
}

// ---------------- Fused cooperative kernel ----------------
__global__ __launch_bounds__(256, 4) void gae_fused(
    const float* __restrict__ value,   // (T+1, B)
    const float* __restrict__ reward,  // (T, B)
    float* __restrict__ S,             // (C, B) workspace
    float* __restrict__ out)           // (T, B)
{
    const int c4    = blockIdx.x * blockDim.x + threadIdx.x;  // column group
    const int chunk = blockIdx.y;
    const size_t b  = (size_t)c4 * 4;
    const int t0    = chunk * L_;

    // Phase 1: load chunk, compute deltas into registers.
    float4 d[L_];
    float4 vnext = *(const float4*)(value + (size_t)(t0 + L_) * B_ + b);
    #pragma unroll
    for (int i = L_ - 1; i >= 0; --i) {
        const int t = t0 + i;
        float4 r = *(const float4*)(reward + (size_t)t * B_ + b);
        float4 v = *(const float4*)(value  + (size_t)t * B_ + b);
        d[i].x = r.x + GAMMA * vnext.x - v.x;
        d[i].y = r.y + GAMMA * vnext.y - v.y;
        d[i].z = r.z + GAMMA * vnext.z - v.z;
        d[i].w = r.w + GAMMA * vnext.w - v.w;
        vnext = v;
    }

    // Chunk-local suffix sum with zero carry -> S[chunk]
    float4 s = make_float4(0.f, 0.f, 0.f, 0.f);
    #pragma unroll
    for (int i = L_ - 1; i >= 0; --i) s = fmaf4(d[i], COEF, s);
    *(float4*)(S + (size_t)chunk * B_ + b) = s;

    cg::this_grid().sync();

    // Phase 2: combine downstream chunk sums (L2-resident, 4 MiB total)
    float4 carry = make_float4(0.f, 0.f, 0.f, 0.f);
    #pragma unroll 4
    for (int j = C_ - 1; j > chunk; --j) {
        float4 sj = *(const float4*)(S + (size_t)j * B_ + b);
        carry = fmaf4(sj, CL, carry);
    }

    // Re-scan from registers with the true carry; emit output.
    float4 a = carry;
    #pragma unroll
    for (int i = L_ - 1; i >= 0; --i) {
        a = fmaf4(d[i], COEF, a);
        *(float4*)(out + (size_t)(t0 + i) * B_ + b) = a;
    }
}

// ---------------- Fallback (non-cooperative) two-pass ----------------
__global__ __launch_bounds__(256) void gae_chunk_scan(
    const float* __restrict__ value,
    const float* __restrict__ reward,
    float* __restrict__ S)
{
    const int c4    = blockIdx.x * blockDim.x + threadIdx.x;
    const int chunk = blockIdx.y;
    const size_t b  = (size_t)c4 * 4;
    const int t0 = chunk * L_;

    float4 vnext = *(const float4*)(value + (size_t)(t0 + L_) * B_ + b);
    float4 s = make_float4(0.f, 0.f, 0.f, 0.f);
    #pragma unroll
    for (int t = t0 + L_ - 1; t >= t0; --t) {
        float4 r = *(const float4*)(reward + (size_t)t * B_ + b);
        float4 v = *(const float4*)(value  + (size_t)t * B_ + b);
        float4 dd;
        dd.x = r.x + GAMMA * vnext.x - v.x;
        dd.y = r.y + GAMMA * vnext.y - v.y;
        dd.z = r.z + GAMMA * vnext.z - v.z;
        dd.w = r.w + GAMMA * vnext.w - v.w;
        s = fmaf4(dd, COEF, s);
        vnext = v;
    }
    *(float4*)(S + (size_t)chunk * B_ + b) = s;
}

__global__ __launch_bounds__(256) void gae_emit(
    const float* __restrict__ value,
    const float* __restrict__ reward,
    const float* __restrict__ S,
    float* __restrict__ out)
{
    const int c4    = blockIdx.x * blockDim.x + threadIdx.x;
    const int chunk = blockIdx.y;
    const size_t b  = (size_t)c4 * 4;
    const int t0 = chunk * L_;

    float4 carry = make_float4(0.f, 0.f, 0.f, 0.f);
    #pragma unroll 4
    for (int j = C_ - 1; j > chunk; --j) {
        float4 sj = *(const float4*)(S + (size_t)j * B_ + b);
        carry = fmaf4(sj, CL, carry);
    }

    float4 a = carry;
    float4 vnext = *(const float4*)(value + (size_t)(t0 + L_) * B_ + b);
    #pragma unroll
    for (int t = t0 + L_ - 1; t >= t0; --t) {
        float4 r = *(const float4*)(reward + (size_t)t * B_ + b);
        float4 v = *(const float4*)(value  + (size_t)t * B_ + b);
        float4 dd;
        dd.x = r.x + GAMMA * vnext.x - v.x;
        dd.y = r.y + GAMMA * vnext.y - v.y;
        dd.z = r.z + GAMMA * vnext.z - v.z;
        dd.w = r.w + GAMMA * vnext.w - v.w;
        a = fmaf4(dd, COEF, a);
        *(float4*)(out + (size_t)t * B_ + b) = a;
        vnext = v;
    }
}

extern "C" void kernel_launch(void* const* d_in, const int* in_sizes, int n_in,
                              void* d_out, int out_size, void* d_ws, size_t ws_size,
                              hipStream_t stream) {
    const float* value  = (const float*)d_in[0];   // (T+1, B)
    const float* reward = (const float*)d_in[1];   // (T, B)
    float* out = (float*)d_out;
    float* S   = (float*)d_ws;                     // C*B*4 = 4 MiB

    dim3 block(256);
    dim3 grid(B_ / 4 / 256, C_);   // (16, 64) = 1024 blocks = 4/CU at >=16 waves/CU

    void* args[] = {(void*)&value, (void*)&reward, (void*)&S, (void*)&out};
    hipError_t err = hipLaunchCooperativeKernel((void*)gae_fused, grid, block,
                                                args, 0, stream);
    if (err != hipSuccess) {
        // Co-residency/capture rejection: deterministic two-pass fallback.
        gae_chunk_scan<<<grid, block, 0, stream>>>(value, reward, S);
        gae_emit<<<grid, block, 0, stream>>>(value, reward, S, out);
    }
}

// Round 3
// 190.347 us; speedup vs baseline: 1.5633x; 1.5633x over previous
//
#include <hip/hip_runtime.h>

// GAE reverse scan: adv[t] = delta[t] + (gamma*lambda)*adv[t+1]
// delta[t] = reward[t] + gamma*value[t+1] - value[t]
//
// 3-pass exact chunked linear recurrence, no serial cross-chunk chains:
//   K1 gae_local : per-(chunk, col4) streaming local suffix scan (zero carry)
//                  -> writes A_loc into out, chunk sum into S.   4096 waves.
//   K2 gae_carry : per-col4 reverse scan over the C=64 chunk sums, IN PLACE:
//                  S[c] <- carry entering chunk c.  Tiny (8 MB L2 traffic).
//   K3 gae_fix   : out[t0+i] += COEF^(L-i) * carry[chunk].  Pure RMW, all
//                  iterations independent.  Chunk C-1 has zero carry -> skipped.

constexpr int T_ = 1024;
constexpr int B_ = 16384;
constexpr int L_ = 16;        // chunk length
constexpr int C_ = T_ / L_;   // 64 chunks
constexpr float GAMMA = 0.99f;
constexpr float COEF  = (float)(0.99 * 0.97);

__host__ __device__ constexpr float pow_coef(int n) {
    float p = 1.0f;
    for (int i = 0; i < n; ++i) p *= COEF;
    return p;
}
constexpr float CL = pow_coef(L_);   // COEF^L

// ---------------- K1: streaming local scan ----------------
__global__ __launch_bounds__(256) void gae_local(
    const float* __restrict__ value,   // (T+1, B)
    const float* __restrict__ reward,  // (T, B)
    float* __restrict__ S,             // (C, B)
    float* __restrict__ out)           // (T, B) <- A_loc
{
    const int c4    = blockIdx.x * 256 + threadIdx.x;
    const int chunk = blockIdx.y;
    const size_t b  = (size_t)c4 * 4;
    const int t0    = chunk * L_;

    float4 vnext = *(const float4*)(value + (size_t)(t0 + L_) * B_ + b);
    float4 a = make_float4(0.f, 0.f, 0.f, 0.f);

    #pragma unroll
    for (int i = L_ - 1; i >= 0; --i) {
        const int t = t0 + i;
        float4 r = *(const float4*)(reward + (size_t)t * B_ + b);
        float4 v = *(const float4*)(value  + (size_t)t * B_ + b);
        a.x = (r.x + GAMMA * vnext.x - v.x) + COEF * a.x;
        a.y = (r.y + GAMMA * vnext.y - v.y) + COEF * a.y;
        a.z = (r.z + GAMMA * vnext.z - v.z) + COEF * a.z;
        a.w = (r.w + GAMMA * vnext.w - v.w) + COEF * a.w;
        *(float4*)(out + (size_t)t * B_ + b) = a;
        vnext = v;
    }
    *(float4*)(S + (size_t)chunk * B_ + b) = a;   // local sum (zero carry)
}

// ---------------- K2: in-place carry scan over chunks ----------------
__global__ __launch_bounds__(256) void gae_carry(float* __restrict__ S)
{
    const int c4   = blockIdx.x * 256 + threadIdx.x;
    const size_t b = (size_t)c4 * 4;

    float4 run = make_float4(0.f, 0.f, 0.f, 0.f);
    #pragma unroll
    for (int j = C_ - 1; j >= 0; --j) {
        float4 s = *(const float4*)(S + (size_t)j * B_ + b);
        *(float4*)(S + (size_t)j * B_ + b) = run;   // carry entering chunk j
        run.x = s.x + CL * run.x;
        run.y = s.y + CL * run.y;
        run.z = s.z + CL * run.z;
        run.w = s.w + CL * run.w;
    }
}

// ---------------- K3: apply carry, independent RMW ----------------
__global__ __launch_bounds__(256) void gae_fix(
    const float* __restrict__ S,   // now holds carries
    float* __restrict__ out)
{
    const int c4    = blockIdx.x * 256 + threadIdx.x;
    const int chunk = blockIdx.y;          // 0..C_-2 (last chunk carry == 0)
    const size_t b  = (size_t)c4 * 4;
    const int t0    = chunk * L_;

    float4 carry = *(const float4*)(S + (size_t)chunk * B_ + b);

    float p = COEF;
    #pragma unroll
    for (int i = L_ - 1; i >= 0; --i) {
        const int t = t0 + i;
        float4 o = *(float4*)(out + (size_t)t * B_ + b);
        o.x += p * carry.x;
        o.y += p * carry.y;
        o.z += p * carry.z;
        o.w += p * carry.w;
        *(float4*)(out + (size_t)t * B_ + b) = o;
        p *= COEF;
    }
}

extern "C" void kernel_launch(void* const* d_in, const int* in_sizes, int n_in,
                              void* d_out, int out_size, void* d_ws, size_t ws_size,
                              hipStream_t stream) {
    const float* value  = (const float*)d_in[0];   // (T+1, B)
    const float* reward = (const float*)d_in[1];   // (T, B)
    float* out = (float*)d_out;
    float* S   = (float*)d_ws;                     // C*B*4 = 4 MiB

    dim3 block(256);
    dim3 gridA(B_ / 4 / 256, C_);       // (16, 64)
    dim3 gridC(B_ / 4 / 256);           // (16)
    dim3 gridF(B_ / 4 / 256, C_ - 1);   // (16, 63): last chunk needs no fix

    gae_local<<<gridA, block, 0, stream>>>(value, reward, S, out);
    gae_carry<<<gridC, block, 0, stream>>>(S);
    gae_fix  <<<gridF, block, 0, stream>>>(S, out);
}

// Round 4
// 189.936 us; speedup vs baseline: 1.5667x; 1.0022x over previous
//
#include <hip/hip_runtime.h>

// GAE reverse scan: adv[t] = delta[t] + (gamma*lambda)*adv[t+1]
// delta[t] = reward[t] + gamma*value[t+1] - value[t]
//
// 3-pass exact chunked linear recurrence. All kernels batch-load their full
// working set into registers BEFORE computing, to maximize loads-in-flight
// (R3 post-mortem: VGPR=32 build kept only ~3 loads outstanding -> 2.3 TB/s).
//   K1 gae_local : per-(chunk, col4) local suffix scan -> out (A_loc), S (sum)
//   K2 gae_carry : per-scalar-column reverse scan over C chunk sums, in place
//   K3 gae_fix   : out[t0+i] += COEF^(L-i) * carry[chunk]  (independent RMW)

constexpr int T_ = 1024;
constexpr int B_ = 16384;
constexpr int L_ = 16;        // chunk length
constexpr int C_ = T_ / L_;   // 64 chunks
constexpr float GAMMA = 0.99f;
constexpr float COEF  = (float)(0.99 * 0.97);

__host__ __device__ constexpr float pow_coef(int n) {
    float p = 1.0f;
    for (int i = 0; i < n; ++i) p *= COEF;
    return p;
}
constexpr float CL = pow_coef(L_);   // COEF^L

// ---------------- K1: batched local scan ----------------
__global__ __launch_bounds__(256) void gae_local(
    const float* __restrict__ value,   // (T+1, B)
    const float* __restrict__ reward,  // (T, B)
    float* __restrict__ S,             // (C, B)
    float* __restrict__ out)           // (T, B) <- A_loc
{
    const int c4    = blockIdx.x * 256 + threadIdx.x;
    const int chunk = blockIdx.y;
    const size_t b  = (size_t)c4 * 4;
    const int t0    = chunk * L_;

    // Batch ALL loads first: 17 value rows + 16 reward rows in flight.
    float4 v[L_ + 1];
    float4 r[L_];
    #pragma unroll
    for (int i = 0; i <= L_; ++i)
        v[i] = *(const float4*)(value + (size_t)(t0 + i) * B_ + b);
    #pragma unroll
    for (int i = 0; i < L_; ++i)
        r[i] = *(const float4*)(reward + (size_t)(t0 + i) * B_ + b);

    float4 a = make_float4(0.f, 0.f, 0.f, 0.f);
    #pragma unroll
    for (int i = L_ - 1; i >= 0; --i) {
        a.x = (r[i].x + GAMMA * v[i + 1].x - v[i].x) + COEF * a.x;
        a.y = (r[i].y + GAMMA * v[i + 1].y - v[i].y) + COEF * a.y;
        a.z = (r[i].z + GAMMA * v[i + 1].z - v[i].z) + COEF * a.z;
        a.w = (r[i].w + GAMMA * v[i + 1].w - v[i].w) + COEF * a.w;
        *(float4*)(out + (size_t)(t0 + i) * B_ + b) = a;
    }
    *(float4*)(S + (size_t)chunk * B_ + b) = a;   // local chunk sum
}

// ---------------- K2: in-place carry scan, one thread per scalar column ----
__global__ __launch_bounds__(256) void gae_carry(float* __restrict__ S)
{
    const int col = blockIdx.x * 256 + threadIdx.x;   // 0..B-1

    float s[C_];
    #pragma unroll
    for (int j = 0; j < C_; ++j)
        s[j] = S[(size_t)j * B_ + col];               // 64 loads in flight

    float run = 0.f;
    #pragma unroll
    for (int j = C_ - 1; j >= 0; --j) {
        S[(size_t)j * B_ + col] = run;                // carry entering chunk j
        run = s[j] + CL * run;
    }
}

// ---------------- K3: batched independent RMW ----------------
__global__ __launch_bounds__(256) void gae_fix(
    const float* __restrict__ S,   // now holds carries
    float* __restrict__ out)
{
    const int c4    = blockIdx.x * 256 + threadIdx.x;
    const int chunk = blockIdx.y;          // 0..C_-2 (last chunk carry == 0)
    const size_t b  = (size_t)c4 * 4;
    const int t0    = chunk * L_;

    float4 carry = *(const float4*)(S + (size_t)chunk * B_ + b);

    float4 o[L_];
    #pragma unroll
    for (int i = 0; i < L_; ++i)
        o[i] = *(const float4*)(out + (size_t)(t0 + i) * B_ + b);

    float p = COEF;
    #pragma unroll
    for (int i = L_ - 1; i >= 0; --i) {
        o[i].x += p * carry.x;
        o[i].y += p * carry.y;
        o[i].z += p * carry.z;
        o[i].w += p * carry.w;
        *(float4*)(out + (size_t)(t0 + i) * B_ + b) = o[i];
        p *= COEF;
    }
}

extern "C" void kernel_launch(void* const* d_in, const int* in_sizes, int n_in,
                              void* d_out, int out_size, void* d_ws, size_t ws_size,
                              hipStream_t stream) {
    const float* value  = (const float*)d_in[0];   // (T+1, B)
    const float* reward = (const float*)d_in[1];   // (T, B)
    float* out = (float*)d_out;
    float* S   = (float*)d_ws;                     // C*B*4 = 4 MiB

    dim3 block(256);
    dim3 gridA(B_ / 4 / 256, C_);       // (16, 64)
    dim3 gridC(B_ / 256);               // (64) scalar columns
    dim3 gridF(B_ / 4 / 256, C_ - 1);   // (16, 63)

    gae_local<<<gridA, block, 0, stream>>>(value, reward, S, out);
    gae_carry<<<gridC, block, 0, stream>>>(S);
    gae_fix  <<<gridF, block, 0, stream>>>(S, out);
}